// Round 1
// baseline (496.230 us; speedup 1.0000x reference)
//
#include <hip/hip_runtime.h>
#include <hip/hip_bf16.h>

typedef float f32x4 __attribute__((ext_vector_type(4)));
typedef short s16x8 __attribute__((ext_vector_type(8)));
typedef unsigned short u16;

#define H_ 16
#define E_ 64
#define D_ 1024
#define L_ 2048

__device__ __forceinline__ u16 f2bf(float f) {
  union { float f; unsigned u; } v; v.f = f;
  unsigned u = v.u;
  u += 0x7fffu + ((u >> 16) & 1u);   // round-to-nearest-even
  return (u16)(u >> 16);
}

// out = A (M x K) * W^T + bias,  W is (N x K) row-major (i.e. B^T input).
// A_BF16: A is bf16 (u16) else f32 (converted on the fly).
// PERMUTE: write bf16 to (B,H,L,E) layout; else write f32 row-major (M x N).
template<int A_BF16, int PERMUTE>
__global__ __launch_bounds__(256) void gemm_bt(const void* __restrict__ Aptr,
                                               const float* __restrict__ W,
                                               const float* __restrict__ bias,
                                               void* __restrict__ outp,
                                               int M, int N, int K)
{
  __shared__ __align__(16) short As[128][40];   // +8 pad: 80B row stride -> 2-way (free)
  __shared__ __align__(16) short Bs[128][40];
  const int tid = threadIdx.x;
  const int m0 = blockIdx.y * 128, n0 = blockIdx.x * 128;
  const int w = tid >> 6, lane = tid & 63, g = lane >> 4, li = lane & 15;
  const int wr = w >> 1, wc = w & 1;

  f32x4 acc[4][4];
#pragma unroll
  for (int i = 0; i < 4; ++i)
#pragma unroll
    for (int j = 0; j < 4; ++j) acc[i][j] = (f32x4){0.f, 0.f, 0.f, 0.f};

  for (int k0 = 0; k0 < K; k0 += 32) {
    __syncthreads();
#pragma unroll
    for (int p = 0; p < 2; ++p) {
      const int c = p * 256 + tid;          // 512 chunks of 8 elems
      const int row = c >> 2, kc = (c & 3) * 8;
      if (A_BF16) {
        const u16* ap = (const u16*)Aptr + (size_t)(m0 + row) * K + k0 + kc;
        *(s16x8*)&As[row][kc] = *(const s16x8*)ap;
      } else {
        const float* ap = (const float*)Aptr + (size_t)(m0 + row) * K + k0 + kc;
        f32x4 f0 = *(const f32x4*)ap, f1 = *(const f32x4*)(ap + 4);
        s16x8 r;
#pragma unroll
        for (int j = 0; j < 4; ++j) { r[j] = (short)f2bf(f0[j]); r[j + 4] = (short)f2bf(f1[j]); }
        *(s16x8*)&As[row][kc] = r;
      }
      const float* wp = W + (size_t)(n0 + row) * K + k0 + kc;
      f32x4 g0 = *(const f32x4*)wp, g1 = *(const f32x4*)(wp + 4);
      s16x8 rb;
#pragma unroll
      for (int j = 0; j < 4; ++j) { rb[j] = (short)f2bf(g0[j]); rb[j + 4] = (short)f2bf(g1[j]); }
      *(s16x8*)&Bs[row][kc] = rb;
    }
    __syncthreads();

    s16x8 a[4], b[4];
#pragma unroll
    for (int mi = 0; mi < 4; ++mi) a[mi] = *(const s16x8*)&As[wr * 64 + mi * 16 + li][g * 8];
#pragma unroll
    for (int ni = 0; ni < 4; ++ni) b[ni] = *(const s16x8*)&Bs[wc * 64 + ni * 16 + li][g * 8];
#pragma unroll
    for (int mi = 0; mi < 4; ++mi)
#pragma unroll
      for (int ni = 0; ni < 4; ++ni)
        acc[mi][ni] = __builtin_amdgcn_mfma_f32_16x16x32_bf16(a[mi], b[ni], acc[mi][ni], 0, 0, 0);
  }

#pragma unroll
  for (int mi = 0; mi < 4; ++mi) {
#pragma unroll
    for (int ni = 0; ni < 4; ++ni) {
      const int row = m0 + wr * 64 + mi * 16 + g * 4;
      const int col = n0 + wc * 64 + ni * 16 + li;
      const float bv = bias[col];
#pragma unroll
      for (int r = 0; r < 4; ++r) {
        const float v = acc[mi][ni][r] + bv;
        const int rr = row + r;
        if (PERMUTE) {
          const int bb = rr >> 11, lq = rr & (L_ - 1);
          const int hh = col >> 6, e = col & (E_ - 1);
          ((u16*)outp)[(((size_t)bb * H_ + hh) * L_ + lq) * E_ + e] = f2bf(v);
        } else {
          ((float*)outp)[(size_t)rr * N + col] = v;
        }
      }
    }
  }
}

// Flash attention, causal. Grid: (L/64, B*H). Block: 256 (4 waves x 16 q rows).
// q/k/v in (B,H,L,E) bf16. Output attn (B*L, D) bf16.
__global__ __launch_bounds__(256) void attn_kernel(const u16* __restrict__ qb_,
                                                   const u16* __restrict__ kb_,
                                                   const u16* __restrict__ vb_,
                                                   u16* __restrict__ ob_)
{
  __shared__ __align__(16) short Ks[64][72];      // K rows (S x E), +8 pad
  __shared__ __align__(16) short Vt[64][72];      // V^T: [e][k]
  __shared__ __align__(16) short Ps[4][16][72];   // per-wave P relayout
  const int tid = threadIdx.x;
  const int qb = blockIdx.x;    // q tile
  const int bh = blockIdx.y;    // b*H + h
  const int w = tid >> 6, lane = tid & 63, g = lane >> 4, li = lane & 15;
  const int qbase = qb * 64;
  const float scale = 0.125f;   // 1/sqrt(E)

  const size_t base = (size_t)bh * L_ * E_;
  const int qrow = qbase + w * 16 + li;
  const s16x8 qa0 = *(const s16x8*)(qb_ + base + (size_t)qrow * E_ + g * 8);
  const s16x8 qa1 = *(const s16x8*)(qb_ + base + (size_t)qrow * E_ + 32 + g * 8);

  f32x4 o[4];
#pragma unroll
  for (int nc = 0; nc < 4; ++nc) o[nc] = (f32x4){0.f, 0.f, 0.f, 0.f};
  float m_run[4], l_run[4];
#pragma unroll
  for (int r = 0; r < 4; ++r) { m_run[r] = -1e30f; l_run[r] = 0.f; }

  for (int t = 0; t <= qb; ++t) {
    const int kvb = t * 64;
#pragma unroll
    for (int p = 0; p < 2; ++p) {
      const int c = p * 256 + tid;           // 512 chunks of 8
      const int kr = c >> 3, e0 = (c & 7) * 8;
      const size_t ga = base + (size_t)(kvb + kr) * E_ + e0;
      *(s16x8*)&Ks[kr][e0] = *(const s16x8*)(kb_ + ga);
      const s16x8 vv = *(const s16x8*)(vb_ + ga);
#pragma unroll
      for (int j = 0; j < 8; ++j) Vt[e0 + j][kr] = vv[j];
    }
    __syncthreads();

    float s[4][4];   // [kc][r]
#pragma unroll
    for (int kc = 0; kc < 4; ++kc) {
      const s16x8 k0 = *(const s16x8*)&Ks[kc * 16 + li][g * 8];
      const s16x8 k1 = *(const s16x8*)&Ks[kc * 16 + li][32 + g * 8];
      f32x4 sf = (f32x4){0.f, 0.f, 0.f, 0.f};
      sf = __builtin_amdgcn_mfma_f32_16x16x32_bf16(qa0, k0, sf, 0, 0, 0);
      sf = __builtin_amdgcn_mfma_f32_16x16x32_bf16(qa1, k1, sf, 0, 0, 0);
#pragma unroll
      for (int r = 0; r < 4; ++r) s[kc][r] = sf[r] * scale;
    }
    if (t == qb) {   // diagonal tile: causal mask (col > row -> -inf)
#pragma unroll
      for (int kc = 0; kc < 4; ++kc) {
        const int col = kvb + kc * 16 + li;
#pragma unroll
        for (int r = 0; r < 4; ++r) {
          const int rowq = qbase + w * 16 + g * 4 + r;
          if (col > rowq) s[kc][r] = -1e30f;
        }
      }
    }
    // online softmax: rows live across 16-lane groups at fixed reg r
#pragma unroll
    for (int r = 0; r < 4; ++r) {
      float mx = fmaxf(fmaxf(s[0][r], s[1][r]), fmaxf(s[2][r], s[3][r]));
#pragma unroll
      for (int off = 1; off <= 8; off <<= 1) mx = fmaxf(mx, __shfl_xor(mx, off));
      const float mn = fmaxf(m_run[r], mx);
      const float alpha = __expf(m_run[r] - mn);
      m_run[r] = mn;
      float rs = 0.f;
#pragma unroll
      for (int kc = 0; kc < 4; ++kc) { const float pv = __expf(s[kc][r] - mn); s[kc][r] = pv; rs += pv; }
#pragma unroll
      for (int off = 1; off <= 8; off <<= 1) rs += __shfl_xor(rs, off);
      l_run[r] = l_run[r] * alpha + rs;
#pragma unroll
      for (int nc = 0; nc < 4; ++nc) o[nc][r] *= alpha;
    }
    // P (D-layout) -> LDS -> A-layout fragments
#pragma unroll
    for (int kc = 0; kc < 4; ++kc)
#pragma unroll
      for (int r = 0; r < 4; ++r)
        Ps[w][g * 4 + r][kc * 16 + li] = (short)f2bf(s[kc][r]);
    const s16x8 pa0 = *(const s16x8*)&Ps[w][li][g * 8];
    const s16x8 pa1 = *(const s16x8*)&Ps[w][li][32 + g * 8];
#pragma unroll
    for (int nc = 0; nc < 4; ++nc) {
      const s16x8 v0 = *(const s16x8*)&Vt[nc * 16 + li][g * 8];
      const s16x8 v1 = *(const s16x8*)&Vt[nc * 16 + li][32 + g * 8];
      o[nc] = __builtin_amdgcn_mfma_f32_16x16x32_bf16(pa0, v0, o[nc], 0, 0, 0);
      o[nc] = __builtin_amdgcn_mfma_f32_16x16x32_bf16(pa1, v1, o[nc], 0, 0, 0);
    }
    __syncthreads();
  }

  const int bb = bh >> 4, hh = bh & 15;
#pragma unroll
  for (int nc = 0; nc < 4; ++nc) {
#pragma unroll
    for (int r = 0; r < 4; ++r) {
      const int rowq = qbase + w * 16 + g * 4 + r;
      const float v = o[nc][r] / l_run[r];
      ob_[((size_t)bb * L_ + rowq) * D_ + hh * E_ + nc * 16 + li] = f2bf(v);
    }
  }
}

extern "C" void kernel_launch(void* const* d_in, const int* in_sizes, int n_in,
                              void* d_out, int out_size, void* d_ws, size_t ws_size,
                              hipStream_t stream) {
  const float* queries = (const float*)d_in[0];
  const float* keys    = (const float*)d_in[1];
  const float* values  = (const float*)d_in[2];
  // d_in[3] = attn_mask: exact causal triu(k=1) mask, applied analytically.
  const float* Wq = (const float*)d_in[4];
  const float* bq = (const float*)d_in[5];
  const float* Wk = (const float*)d_in[6];
  const float* bk = (const float*)d_in[7];
  const float* Wv = (const float*)d_in[8];
  const float* bv = (const float*)d_in[9];
  const float* Wo = (const float*)d_in[10];
  const float* bo = (const float*)d_in[11];

  const size_t MD = (size_t)8192 * 1024;
  u16* qbuf = (u16*)d_ws;          // (B,H,L,E) bf16, 16 MB
  u16* kbuf = qbuf + MD;
  u16* vbuf = kbuf + MD;
  u16* abuf = vbuf + MD;           // attn out (B*L, D) bf16

  dim3 blk(256);
  dim3 ggrid(8, 64);               // (N/128, M/128)
  gemm_bt<0, 1><<<ggrid, blk, 0, stream>>>(queries, Wq, bq, qbuf, 8192, 1024, 1024);
  gemm_bt<0, 1><<<ggrid, blk, 0, stream>>>(keys,    Wk, bk, kbuf, 8192, 1024, 1024);
  gemm_bt<0, 1><<<ggrid, blk, 0, stream>>>(values,  Wv, bv, vbuf, 8192, 1024, 1024);
  attn_kernel<<<dim3(32, 64), blk, 0, stream>>>(qbuf, kbuf, vbuf, abuf);
  gemm_bt<1, 0><<<ggrid, blk, 0, stream>>>(abuf, Wo, bo, d_out, 8192, 1024, 1024);
}

// Round 2
// 461.538 us; speedup vs baseline: 1.0752x; 1.0752x over previous
//
#include <hip/hip_runtime.h>
#include <hip/hip_bf16.h>

typedef float f32x4 __attribute__((ext_vector_type(4)));
typedef short s16x8 __attribute__((ext_vector_type(8)));
typedef short s16x4 __attribute__((ext_vector_type(4)));
typedef unsigned short u16;

#define H_ 16
#define E_ 64
#define D_ 1024
#define L_ 2048
#define NQT 32   // 64-row q tiles per (b,h)

__device__ __forceinline__ u16 f2bf(float f) {
  union { float f; unsigned u; } v; v.f = f;
  unsigned u = v.u;
  u += 0x7fffu + ((u >> 16) & 1u);   // round-to-nearest-even
  return (u16)(u >> 16);
}

// out = A (M x K) * W^T + bias,  W is (N x K) row-major.
// A_BF16: A is bf16 (u16) else f32 (converted on the fly).
// PERMUTE: 0 = f32 row-major (M x N); 1 = bf16 (B,H,L,E); 2 = bf16 (B,H,E,L) (V^T).
template<int A_BF16, int PERMUTE>
__global__ __launch_bounds__(256) void gemm_bt(const void* __restrict__ Aptr,
                                               const float* __restrict__ W,
                                               const float* __restrict__ bias,
                                               void* __restrict__ outp,
                                               int M, int N, int K)
{
  __shared__ __align__(16) short As[128][40];   // +8 pad: 80B stride -> 2-way (free)
  __shared__ __align__(16) short Bs[128][40];
  const int tid = threadIdx.x;
  const int m0 = blockIdx.y * 128, n0 = blockIdx.x * 128;
  const int w = tid >> 6, lane = tid & 63, g = lane >> 4, li = lane & 15;
  const int wr = w >> 1, wc = w & 1;

  f32x4 acc[4][4];
#pragma unroll
  for (int i = 0; i < 4; ++i)
#pragma unroll
    for (int j = 0; j < 4; ++j) acc[i][j] = (f32x4){0.f, 0.f, 0.f, 0.f};

  for (int k0 = 0; k0 < K; k0 += 32) {
    __syncthreads();
#pragma unroll
    for (int p = 0; p < 2; ++p) {
      const int c = p * 256 + tid;          // 512 chunks of 8 elems
      const int row = c >> 2, kc = (c & 3) * 8;
      if (A_BF16) {
        const u16* ap = (const u16*)Aptr + (size_t)(m0 + row) * K + k0 + kc;
        *(s16x8*)&As[row][kc] = *(const s16x8*)ap;
      } else {
        const float* ap = (const float*)Aptr + (size_t)(m0 + row) * K + k0 + kc;
        f32x4 f0 = *(const f32x4*)ap, f1 = *(const f32x4*)(ap + 4);
        s16x8 r;
#pragma unroll
        for (int j = 0; j < 4; ++j) { r[j] = (short)f2bf(f0[j]); r[j + 4] = (short)f2bf(f1[j]); }
        *(s16x8*)&As[row][kc] = r;
      }
      const float* wp = W + (size_t)(n0 + row) * K + k0 + kc;
      f32x4 g0 = *(const f32x4*)wp, g1 = *(const f32x4*)(wp + 4);
      s16x8 rb;
#pragma unroll
      for (int j = 0; j < 4; ++j) { rb[j] = (short)f2bf(g0[j]); rb[j + 4] = (short)f2bf(g1[j]); }
      *(s16x8*)&Bs[row][kc] = rb;
    }
    __syncthreads();

    s16x8 a[4], b[4];
#pragma unroll
    for (int mi = 0; mi < 4; ++mi) a[mi] = *(const s16x8*)&As[wr * 64 + mi * 16 + li][g * 8];
#pragma unroll
    for (int ni = 0; ni < 4; ++ni) b[ni] = *(const s16x8*)&Bs[wc * 64 + ni * 16 + li][g * 8];
#pragma unroll
    for (int mi = 0; mi < 4; ++mi)
#pragma unroll
      for (int ni = 0; ni < 4; ++ni)
        acc[mi][ni] = __builtin_amdgcn_mfma_f32_16x16x32_bf16(a[mi], b[ni], acc[mi][ni], 0, 0, 0);
  }

#pragma unroll
  for (int mi = 0; mi < 4; ++mi) {
#pragma unroll
    for (int ni = 0; ni < 4; ++ni) {
      const int row = m0 + wr * 64 + mi * 16 + g * 4;
      const int col = n0 + wc * 64 + ni * 16 + li;
      const float bv = bias[col];
      if (PERMUTE == 2) {
        s16x4 pk;
#pragma unroll
        for (int r = 0; r < 4; ++r) pk[r] = (short)f2bf(acc[mi][ni][r] + bv);
        const int bb = row >> 11, lq = row & (L_ - 1);
        const int hh = col >> 6, e = col & (E_ - 1);
        *(s16x4*)&((u16*)outp)[(((size_t)bb * H_ + hh) * E_ + e) * L_ + lq] = pk;
      } else {
#pragma unroll
        for (int r = 0; r < 4; ++r) {
          const float v = acc[mi][ni][r] + bv;
          const int rr = row + r;
          if (PERMUTE == 1) {
            const int bb = rr >> 11, lq = rr & (L_ - 1);
            const int hh = col >> 6, e = col & (E_ - 1);
            ((u16*)outp)[(((size_t)bb * H_ + hh) * L_ + lq) * E_ + e] = f2bf(v);
          } else {
            ((float*)outp)[(size_t)rr * N + col] = v;
          }
        }
      }
    }
  }
}

// Flash attention, causal. Grid: (NQT/2, B*H). Block: 256 (4 waves x 16 q rows).
// q,k in (B,H,L,E) bf16; v in (B,H,E,L) bf16 (pre-transposed by V GEMM).
// K/V fragments are loaded DIRECTLY from global (L2-resident, 512KB per bh):
// no LDS staging, no barriers. Each block does q-tiles {x, 31-x} (33 KV tiles).
__global__ __launch_bounds__(256) void attn_kernel(const u16* __restrict__ qp,
                                                   const u16* __restrict__ kp,
                                                   const u16* __restrict__ vtp,
                                                   u16* __restrict__ op)
{
  __shared__ __align__(16) short Ps[4][16][72];   // per-wave P relayout (no barriers)
  const int tid = threadIdx.x;
  const int bh = blockIdx.y;
  const int w = tid >> 6, lane = tid & 63, g = lane >> 4, li = lane & 15;
  const float scale = 0.125f;                     // 1/sqrt(E)
  const size_t base  = (size_t)bh * L_ * E_;      // q,k: (B,H,L,E)
  const size_t baseT = (size_t)bh * E_ * L_;      // vt:  (B,H,E,L)
  const int bb = bh >> 4, hh = bh & 15;

  for (int pi = 0; pi < 2; ++pi) {
    const int qb = pi ? (NQT - 1 - (int)blockIdx.x) : (int)blockIdx.x;
    const int qbase = qb * 64;
    const int qrow = qbase + w * 16 + li;
    const u16* qr = qp + base + (size_t)qrow * E_;
    const s16x8 qa0 = *(const s16x8*)(qr + g * 8);
    const s16x8 qa1 = *(const s16x8*)(qr + 32 + g * 8);

    f32x4 o[4];
#pragma unroll
    for (int nc = 0; nc < 4; ++nc) o[nc] = (f32x4){0.f, 0.f, 0.f, 0.f};
    float m_run[4], l_run[4];
#pragma unroll
    for (int r = 0; r < 4; ++r) { m_run[r] = -1e30f; l_run[r] = 0.f; }

    for (int t = 0; t <= qb; ++t) {
      const int kvb = t * 64;
      float s[4][4];   // [kc][r]
#pragma unroll
      for (int kc = 0; kc < 4; ++kc) {
        const u16* krow = kp + base + (size_t)(kvb + kc * 16 + li) * E_;
        const s16x8 k0 = *(const s16x8*)(krow + g * 8);
        const s16x8 k1 = *(const s16x8*)(krow + 32 + g * 8);
        f32x4 sf = (f32x4){0.f, 0.f, 0.f, 0.f};
        sf = __builtin_amdgcn_mfma_f32_16x16x32_bf16(qa0, k0, sf, 0, 0, 0);
        sf = __builtin_amdgcn_mfma_f32_16x16x32_bf16(qa1, k1, sf, 0, 0, 0);
#pragma unroll
        for (int r = 0; r < 4; ++r) s[kc][r] = sf[r] * scale;
      }
      if (t == qb) {   // diagonal tile: causal mask (col > row -> -inf)
#pragma unroll
        for (int kc = 0; kc < 4; ++kc) {
          const int col = kvb + kc * 16 + li;
#pragma unroll
          for (int r = 0; r < 4; ++r) {
            const int rowq = qbase + w * 16 + g * 4 + r;
            if (col > rowq) s[kc][r] = -1e30f;
          }
        }
      }
      // online softmax: a q-row lives across the 16-lane group at fixed reg r
#pragma unroll
      for (int r = 0; r < 4; ++r) {
        float mx = fmaxf(fmaxf(s[0][r], s[1][r]), fmaxf(s[2][r], s[3][r]));
#pragma unroll
        for (int off = 1; off <= 8; off <<= 1) mx = fmaxf(mx, __shfl_xor(mx, off));
        const float mn = fmaxf(m_run[r], mx);
        const float alpha = __expf(m_run[r] - mn);
        m_run[r] = mn;
        float rs = 0.f;
#pragma unroll
        for (int kc = 0; kc < 4; ++kc) { const float pv = __expf(s[kc][r] - mn); s[kc][r] = pv; rs += pv; }
#pragma unroll
        for (int off = 1; off <= 8; off <<= 1) rs += __shfl_xor(rs, off);
        l_run[r] = l_run[r] * alpha + rs;
#pragma unroll
        for (int nc = 0; nc < 4; ++nc) o[nc][r] *= alpha;
      }
      // P (D-layout) -> per-wave LDS -> A-layout fragments (wave-internal, no barrier)
#pragma unroll
      for (int kc = 0; kc < 4; ++kc)
#pragma unroll
        for (int r = 0; r < 4; ++r)
          Ps[w][g * 4 + r][kc * 16 + li] = (short)f2bf(s[kc][r]);
      const s16x8 pa0 = *(const s16x8*)&Ps[w][li][g * 8];
      const s16x8 pa1 = *(const s16x8*)&Ps[w][li][32 + g * 8];
#pragma unroll
      for (int nc = 0; nc < 4; ++nc) {
        const u16* vrow = vtp + baseT + (size_t)(nc * 16 + li) * L_ + kvb;
        const s16x8 v0 = *(const s16x8*)(vrow + g * 8);
        const s16x8 v1 = *(const s16x8*)(vrow + 32 + g * 8);
        o[nc] = __builtin_amdgcn_mfma_f32_16x16x32_bf16(pa0, v0, o[nc], 0, 0, 0);
        o[nc] = __builtin_amdgcn_mfma_f32_16x16x32_bf16(pa1, v1, o[nc], 0, 0, 0);
      }
    }

#pragma unroll
    for (int nc = 0; nc < 4; ++nc) {
#pragma unroll
      for (int r = 0; r < 4; ++r) {
        const int rowq = qbase + w * 16 + g * 4 + r;
        const float v = o[nc][r] / l_run[r];
        op[((size_t)bb * L_ + rowq) * D_ + hh * E_ + nc * 16 + li] = f2bf(v);
      }
    }
  }
}

extern "C" void kernel_launch(void* const* d_in, const int* in_sizes, int n_in,
                              void* d_out, int out_size, void* d_ws, size_t ws_size,
                              hipStream_t stream) {
  const float* queries = (const float*)d_in[0];
  const float* keys    = (const float*)d_in[1];
  const float* values  = (const float*)d_in[2];
  // d_in[3] = attn_mask: exact causal triu(k=1), applied analytically.
  const float* Wq = (const float*)d_in[4];
  const float* bq = (const float*)d_in[5];
  const float* Wk = (const float*)d_in[6];
  const float* bk = (const float*)d_in[7];
  const float* Wv = (const float*)d_in[8];
  const float* bv = (const float*)d_in[9];
  const float* Wo = (const float*)d_in[10];
  const float* bo = (const float*)d_in[11];

  const size_t MD = (size_t)8192 * 1024;
  u16* qbuf = (u16*)d_ws;          // (B,H,L,E) bf16
  u16* kbuf = qbuf + MD;           // (B,H,L,E) bf16
  u16* vbuf = kbuf + MD;           // (B,H,E,L) bf16 (V^T)
  u16* abuf = vbuf + MD;           // attn out (B*L, D) bf16

  dim3 blk(256);
  dim3 ggrid(8, 64);               // (N/128, M/128)
  gemm_bt<0, 1><<<ggrid, blk, 0, stream>>>(queries, Wq, bq, qbuf, 8192, 1024, 1024);
  gemm_bt<0, 1><<<ggrid, blk, 0, stream>>>(keys,    Wk, bk, kbuf, 8192, 1024, 1024);
  gemm_bt<0, 2><<<ggrid, blk, 0, stream>>>(values,  Wv, bv, vbuf, 8192, 1024, 1024);
  attn_kernel<<<dim3(NQT / 2, 64), blk, 0, stream>>>(qbuf, kbuf, vbuf, abuf);
  gemm_bt<1, 0><<<ggrid, blk, 0, stream>>>(abuf, Wo, bo, d_out, 8192, 1024, 1024);
}